// Round 7
// baseline (307.441 us; speedup 1.0000x reference)
//
#include <hip/hip_runtime.h>

// Problem constants
#define BATCH 4
#define SEQ 2048
#define DM 1024
#define NH 16
#define DK 64

typedef unsigned short u16;
typedef unsigned int u32;
typedef __attribute__((ext_vector_type(8))) short bfrag;    // 8 bf16 (MFMA x32 A/B)
typedef __attribute__((ext_vector_type(4))) short bfrag4;   // 4 bf16 (MFMA x16 A/B)
typedef __attribute__((ext_vector_type(4))) float ffrag;    // 4 fp32 (MFMA C/D)

__device__ inline u16 f2bf(float f) {
  union { float f; u32 u; } v; v.f = f;
  u32 u = v.u;
  return (u16)((u + 0x7FFFu + ((u >> 16) & 1u)) >> 16);  // RNE
}
__device__ inline ffrag MFMA(bfrag a, bfrag b, ffrag c) {
  return __builtin_amdgcn_mfma_f32_16x16x32_bf16(a, b, c, 0, 0, 0);
}
// Device pass only (host __has_builtin is false — R4 lesson). Host gets a stub.
#if defined(__has_builtin)
#if __has_builtin(__builtin_amdgcn_mfma_f32_16x16x16bf16_1k)
#define HAVE_MFMA16 1
#endif
#endif
#if HAVE_MFMA16
__device__ inline ffrag MFMA16(bfrag4 a, bfrag4 b, ffrag c) {
  return __builtin_amdgcn_mfma_f32_16x16x16bf16_1k(a, b, c, 0, 0, 0);
}
#else
__device__ inline ffrag MFMA16(bfrag4 a, bfrag4 b, ffrag c) { return c; }  // host stub
#endif

// async global -> LDS, 16 bytes per lane (wave-uniform base + lane*16)
__device__ __forceinline__ void g2l16(const u16* g, u16* l) {
  __builtin_amdgcn_global_load_lds(
      (const __attribute__((address_space(1))) u16*)g,
      (__attribute__((address_space(3))) u16*)l, 16, 0, 0);
}

// ---------------- fp32 -> bf16 conversion
__global__ __launch_bounds__(256) void cvt_bf16(const float* __restrict__ in,
                                                u16* __restrict__ out, int n4) {
  int i = blockIdx.x * 256 + threadIdx.x;
  if (i >= n4) return;
  float4 v = ((const float4*)in)[i];
  union { u16 u[4]; uint2 d; } o;
  o.u[0] = f2bf(v.x); o.u[1] = f2bf(v.y); o.u[2] = f2bf(v.z); o.u[3] = f2bf(v.w);
  ((uint2*)out)[i] = o.d;
}

// fused 4-weight conversion; Wq is pre-scaled by 0.125*log2(e) so attention
// scores come out of QK^T already in exp2 domain (saves a per-block Q repack).
__global__ __launch_bounds__(256) void cvt_w4(
    const float* __restrict__ a, const float* __restrict__ b,
    const float* __restrict__ c, const float* __restrict__ d,
    u16* __restrict__ oa, u16* __restrict__ ob,
    u16* __restrict__ oc, u16* __restrict__ od) {
  int which = blockIdx.x >> 10;
  int i = (blockIdx.x & 1023) * 256 + threadIdx.x;
  const float* in = which == 0 ? a : which == 1 ? b : which == 2 ? c : d;
  u16* out = which == 0 ? oa : which == 1 ? ob : which == 2 ? oc : od;
  float sc = (which == 0) ? 0.18033688011112042f : 1.0f;  // 0.125*log2e
  float4 v = ((const float4*)in)[i];
  union { u16 u[4]; uint2 dd; } o;
  o.u[0] = f2bf(v.x * sc); o.u[1] = f2bf(v.y * sc);
  o.u[2] = f2bf(v.z * sc); o.u[3] = f2bf(v.w * sc);
  ((uint2*)out)[i] = o.dd;
}

// ---------------- fused Q/K/V projection. z=0: Q row-layout [B,H,S,DK].
// z=1: K swizzled per 64-kv tile (lane-linear image of attn's x32 A-frags).
// z=2: V^T swizzled (lane-linear image of attn's x16 A-frags), computed with
// swapped operand roles. Epilogue: each wave's 64x64 output is exactly one
// contiguous 8KB image -> build it in per-wave LDS (reusing As/Bs in two
// wave-pair rounds), then 8 coalesced dwordx4 stores per lane.
__global__ __launch_bounds__(256) void gemm_qkv(
    const u16* __restrict__ xb,
    const u16* __restrict__ Wq, const u16* __restrict__ Wk,
    const u16* __restrict__ Wv,
    u16* __restrict__ Qb, u16* __restrict__ Ksw, u16* __restrict__ Vsw) {
  const int z = blockIdx.z;
  const u16* Bm = z == 0 ? Wq : z == 1 ? Wk : Wv;

  const int K = DM;
  const int bm = blockIdx.y * 128, bn = blockIdx.x * 128;
  __shared__ __align__(16) u16 As[128 * 32];
  __shared__ __align__(16) u16 Bs[128 * 32];
  const int tid = threadIdx.x;
  const int lane = tid & 63;
  const int w = tid >> 6;
  const int wr = w >> 1, wc = w & 1;
  const int l15 = lane & 15, quad = lane >> 4;
  const int srow = tid >> 2, scol = (tid & 3) * 8;

  ffrag acc[4][4] = {};

  for (int k0 = 0; k0 < K; k0 += 32) {
    __syncthreads();
    g2l16(&xb[(size_t)(bm + srow) * K + k0 + scol], &As[tid * 8]);
    g2l16(&xb[(size_t)(bm + 64 + srow) * K + k0 + scol], &As[(tid + 256) * 8]);
    g2l16(&Bm[(size_t)(bn + srow) * K + k0 + scol], &Bs[tid * 8]);
    g2l16(&Bm[(size_t)(bn + 64 + srow) * K + k0 + scol], &Bs[(tid + 256) * 8]);
    __syncthreads();
    bfrag af[4], bf[4];
    if (z < 2) {
#pragma unroll
      for (int i = 0; i < 4; i++)
        af[i] = *(const bfrag*)(&As[(wr * 64 + i * 16 + l15) * 32 + quad * 8]);
#pragma unroll
      for (int j = 0; j < 4; j++)
        bf[j] = *(const bfrag*)(&Bs[(wc * 64 + j * 16 + l15) * 32 + quad * 8]);
    } else {   // V: A = W (out-dims as m), B = x^T (tokens as n)
#pragma unroll
      for (int i = 0; i < 4; i++)
        af[i] = *(const bfrag*)(&Bs[(wr * 64 + i * 16 + l15) * 32 + quad * 8]);
#pragma unroll
      for (int j = 0; j < 4; j++)
        bf[j] = *(const bfrag*)(&As[(wc * 64 + j * 16 + l15) * 32 + quad * 8]);
    }
#pragma unroll
    for (int i = 0; i < 4; i++)
#pragma unroll
      for (int j = 0; j < 4; j++)
        acc[i][j] = MFMA(af[i], bf[j], acc[i][j]);
  }

  __syncthreads();   // all K-loop LDS reads done before image writes
  u16* img = (w & 1) ? Bs : As;
  const int tokbase = (z == 2) ? (bm + wc * 64) : (bm + wr * 64);
  const int nbase   = (z == 2) ? (bn + wr * 64) : (bn + wc * 64);
  const int bb = tokbase >> 11, s0 = tokbase & 2047, h = nbase >> 6;
  u16* gp;
  if (z == 0) gp = Qb + (((size_t)(bb * NH + h)) * SEQ + s0) * DK;
  else gp = (z == 1 ? Ksw : Vsw) + (size_t)(bb * NH + h) * (SEQ * DK) +
            (size_t)(s0 >> 6) * 4096;

  for (int pass = 0; pass < 2; pass++) {
    if ((w >> 1) == pass) {
      if (z == 0) {
#pragma unroll
        for (int i = 0; i < 4; i++)
#pragma unroll
          for (int j = 0; j < 4; j++)
#pragma unroll
            for (int r = 0; r < 4; r++)
              img[(i * 16 + quad * 4 + r) * 64 + j * 16 + l15] = f2bf(acc[i][j][r]);
      } else if (z == 1) {
#pragma unroll
        for (int i = 0; i < 4; i++)
#pragma unroll
          for (int j = 0; j < 4; j++)
#pragma unroll
            for (int r = 0; r < 4; r++)
              img[((i * 2 + (j >> 1)) * 64 + ((j & 1) * 2 + (l15 >> 3)) * 16 +
                   quad * 4 + r) * 8 + (l15 & 7)] = f2bf(acc[i][j][r]);
      } else {
#pragma unroll
        for (int i = 0; i < 4; i++)
#pragma unroll
          for (int j = 0; j < 4; j++)
#pragma unroll
            for (int r = 0; r < 4; r++)
              img[((i * 4 + j) * 64 + (l15 >> 2) * 16 + quad * 4 + r) * 4 +
                  (l15 & 3)] = f2bf(acc[i][j][r]);
      }
#pragma unroll
      for (int c = 0; c < 8; c++) {
        int idx = (c * 64 + lane) * 8;
        *(int4*)(&gp[idx]) = *(const int4*)(&img[idx]);
      }
    }
    if (pass == 0) __syncthreads();
  }
}

// ---------------- out projection GEMM: out = Ab @ Wout^T, fp32 output
__global__ __launch_bounds__(256) void gemm_out(
    const u16* __restrict__ Ab, const u16* __restrict__ Wo, float* __restrict__ C) {
  const int K = DM, N = DM;
  const int bm = blockIdx.y * 128, bn = blockIdx.x * 128;
  __shared__ __align__(16) u16 As[128 * 32];
  __shared__ __align__(16) u16 Bs[128 * 32];
  const int tid = threadIdx.x;
  const int lane = tid & 63;
  const int w = tid >> 6;
  const int wr = w >> 1, wc = w & 1;
  const int l15 = lane & 15, quad = lane >> 4;
  const int srow = tid >> 2, scol = (tid & 3) * 8;

  ffrag acc[4][4] = {};

  for (int k0 = 0; k0 < K; k0 += 32) {
    __syncthreads();
    g2l16(&Ab[(size_t)(bm + srow) * K + k0 + scol], &As[tid * 8]);
    g2l16(&Ab[(size_t)(bm + 64 + srow) * K + k0 + scol], &As[(tid + 256) * 8]);
    g2l16(&Wo[(size_t)(bn + srow) * K + k0 + scol], &Bs[tid * 8]);
    g2l16(&Wo[(size_t)(bn + 64 + srow) * K + k0 + scol], &Bs[(tid + 256) * 8]);
    __syncthreads();
    bfrag af[4], bf[4];
#pragma unroll
    for (int i = 0; i < 4; i++)
      af[i] = *(const bfrag*)(&As[(wr * 64 + i * 16 + l15) * 32 + quad * 8]);
#pragma unroll
    for (int j = 0; j < 4; j++)
      bf[j] = *(const bfrag*)(&Bs[(wc * 64 + j * 16 + l15) * 32 + quad * 8]);
#pragma unroll
    for (int i = 0; i < 4; i++)
#pragma unroll
      for (int j = 0; j < 4; j++)
        acc[i][j] = MFMA(af[i], bf[j], acc[i][j]);
  }

#pragma unroll
  for (int i = 0; i < 4; i++)
#pragma unroll
    for (int j = 0; j < 4; j++)
#pragma unroll
      for (int r = 0; r < 4; r++) {
        int m = bm + wr * 64 + i * 16 + quad * 4 + r;
        int n = bn + wc * 64 + j * 16 + l15;
        C[(size_t)m * N + n] = acc[i][j][r];
      }
}

// ---------------- Flash attention.
// K and V staged via g2l16 DMA from swizzled global layouts into double
// buffers; compute phase reads ONLY LDS (lane-linear, conflict-free). R6
// structure; R7 cuts VALU: Q pre-scaled in weights (no repack), P packed via
// v_perm_b32 (1 op vs and+shr+or), and lsum computed on the MATRIX pipe via a
// ones-A-fragment MFMA16 (sums the same truncated-bf16 P, fully reduced
// across quads — no masking, no adds, no final shuffles).
__global__ __launch_bounds__(256) void attn(
    const u16* __restrict__ Qb, const u16* __restrict__ Ksw,
    const u16* __restrict__ Vsw, u16* __restrict__ Ab) {
  const int bh = blockIdx.y;
  const int b = bh >> 4, h = bh & 15;
  const int qbase = blockIdx.x * 128;
  const int tid = threadIdx.x;
  const int w = tid >> 6, lane = tid & 63;
  const int l15 = lane & 15, quad = lane >> 4;

  __shared__ __align__(16) u16 Kt[2][4096];   // swizzled 64x64 K tile, dbuf
  __shared__ __align__(16) u16 Vt[2][4096];   // swizzled 64x64 V tile, dbuf

  const size_t hbase = (size_t)bh * SEQ * DK;

  // Q fragments (B-operand: n=q=l15, k=d=quad*8+e); scale baked into Wq.
  bfrag q[2][2];
#pragma unroll
  for (int i = 0; i < 2; i++)
#pragma unroll
    for (int kk = 0; kk < 2; kk++)
      q[i][kk] = *(const bfrag*)(&Qb[hbase +
          (size_t)(qbase + w * 32 + i * 16 + l15) * DK + kk * 32 + quad * 8]);

  const bfrag4 ones = {(short)0x3F80, (short)0x3F80, (short)0x3F80, (short)0x3F80};
  ffrag O[4][2] = {};      // O^T accs: [d-block][q-block]
  ffrag Lacc[2] = {};      // row-sum accs via ones-MFMA

  // prefetch tile 0
  {
    const u16* ks = &Ksw[hbase];
    const u16* vs = &Vsw[hbase];
    g2l16(&ks[tid * 8], &Kt[0][tid * 8]);
    g2l16(&ks[2048 + tid * 8], &Kt[0][2048 + tid * 8]);
    g2l16(&vs[tid * 8], &Vt[0][tid * 8]);
    g2l16(&vs[2048 + tid * 8], &Vt[0][2048 + tid * 8]);
  }

  for (int t = 0; t < SEQ / 64; t++) {
    const int buf = t & 1;
    __syncthreads();   // DMA for tile t complete; prior reads of buf^1 done
    if (t + 1 < SEQ / 64) {
      const u16* ks = &Ksw[hbase + (size_t)(t + 1) * 4096];
      const u16* vs = &Vsw[hbase + (size_t)(t + 1) * 4096];
      g2l16(&ks[tid * 8], &Kt[buf ^ 1][tid * 8]);
      g2l16(&ks[2048 + tid * 8], &Kt[buf ^ 1][2048 + tid * 8]);
      g2l16(&vs[tid * 8], &Vt[buf ^ 1][tid * 8]);
      g2l16(&vs[2048 + tid * 8], &Vt[buf ^ 1][2048 + tid * 8]);
    }

    bfrag4 pb[4][2];
#pragma unroll
    for (int j = 0; j < 4; j++) {     // kv 16-block
      bfrag k0f = *(const bfrag*)(&Kt[buf][((j * 2 + 0) * 64 + lane) * 8]);
      bfrag k1f = *(const bfrag*)(&Kt[buf][((j * 2 + 1) * 64 + lane) * 8]);
#pragma unroll
      for (int i = 0; i < 2; i++) {   // q 16-block
        ffrag z = {};
        z = MFMA(k0f, q[i][0], z);
        z = MFMA(k1f, q[i][1], z);    // S^T block: lane (q=l15, s=quad*4+r)
        u32 u[4];
#pragma unroll
        for (int r = 0; r < 4; r++)
          u[r] = __float_as_uint(__builtin_amdgcn_exp2f(z[r]));
        union { u32 d[2]; bfrag4 v; } pk;
        pk.d[0] = __builtin_amdgcn_perm(u[1], u[0], 0x07060302u);  // trunc pack
        pk.d[1] = __builtin_amdgcn_perm(u[3], u[2], 0x07060302u);
        pb[j][i] = pk.v;
        Lacc[i] = MFMA16(ones, pk.v, Lacc[i]);   // row-sum on matrix pipe
      }
    }

    // O^T += V^T . P^T : A-frags lane-linear b64 from swizzled V tile
#pragma unroll
    for (int j = 0; j < 4; j++)
#pragma unroll
      for (int db = 0; db < 4; db++) {
        bfrag4 vf = *(const bfrag4*)(&Vt[buf][((db * 4 + j) * 64 + lane) * 4]);
        O[db][0] = MFMA16(vf, pb[j][0], O[db][0]);
        O[db][1] = MFMA16(vf, pb[j][1], O[db][1]);
      }
  }

  // Lacc rows are all identical and fully reduced across quads already.
  float rl[2] = {1.0f / Lacc[0][0], 1.0f / Lacc[1][0]};

  // O^T C-layout: lane holds q=l15, d=quad*4+r. Pack 4 d (8B) per store.
  const size_t obase = ((size_t)b * SEQ) * DM + (size_t)h * DK;
#pragma unroll
  for (int db = 0; db < 4; db++)
#pragma unroll
    for (int i = 0; i < 2; i++) {
      int s = qbase + w * 32 + i * 16 + l15;
      union { u16 u[4]; uint2 d; } o;
#pragma unroll
      for (int r = 0; r < 4; r++) o.u[r] = f2bf(O[db][i][r] * rl[i]);
      *(uint2*)(&Ab[obase + (size_t)s * DM + db * 16 + quad * 4]) = o.d;
    }
}

extern "C" void kernel_launch(void* const* d_in, const int* in_sizes, int n_in,
                              void* d_out, int out_size, void* d_ws, size_t ws_size,
                              hipStream_t stream) {
  const float* x  = (const float*)d_in[0];
  const float* Wq = (const float*)d_in[1];
  const float* Wk = (const float*)d_in[2];
  const float* Wv = (const float*)d_in[3];
  const float* Wo = (const float*)d_in[4];
  float* out = (float*)d_out;

  char* ws = (char*)d_ws;
  u16* xb  = (u16*)(ws + 0);          // 16 MB
  u16* Wqb = (u16*)(ws + 16777216);
  u16* Wkb = (u16*)(ws + 18874368);
  u16* Wvb = (u16*)(ws + 20971520);
  u16* Wob = (u16*)(ws + 23068672);
  u16* Qb  = (u16*)(ws + 25165824);   // [B,H,S,DK]
  u16* Ksw = (u16*)(ws + 41943040);   // [B,H] x 32 tiles x swizzled 64x64
  u16* Vsw = (u16*)(ws + 58720256);   // [B,H] x 32 tiles x swizzled 64x64
  u16* Ab  = (u16*)(ws + 75497472);   // [B,S,DM]
  const size_t NEED = 92274688;
  if (ws_size < NEED) return;

  cvt_bf16<<<8192, 256, 0, stream>>>(x, xb, (BATCH * SEQ * DM) / 4);
  cvt_w4<<<4096, 256, 0, stream>>>(Wq, Wk, Wv, Wo, Wqb, Wkb, Wvb, Wob);

  dim3 gqkv(DM / 128, (BATCH * SEQ) / 128, 3);
  gemm_qkv<<<gqkv, 256, 0, stream>>>(xb, Wqb, Wkb, Wvb, Qb, Ksw, Vsw);

  dim3 gat(SEQ / 128, BATCH * NH);
  attn<<<gat, 256, 0, stream>>>(Qb, Ksw, Vsw, Ab);

  dim3 gout(DM / 128, (BATCH * SEQ) / 128);
  gemm_out<<<gout, 256, 0, stream>>>(Ab, Wob, out);
}